// Round 12
// baseline (703.213 us; speedup 1.0000x reference)
//
#include <hip/hip_runtime.h>
#include <stdint.h>

#define TOK   8192        // 8 frames * 1024 tokens
#define DIM   640
#define HEADS 8
#define HD    80
#define SEQ   1024
#define CROSS 768
#define ETOK  616         // 8 * 77 encoder tokens
#define FFI   2560        // FF inner (half of 5120 proj)
#define SCALE 0.11180339887498949f

typedef unsigned short u16;
typedef unsigned int   u32;

using bf8   = __attribute__((ext_vector_type(8))) short;   // 8 bf16 (4 VGPRs)
using f32x4 = __attribute__((ext_vector_type(4))) float;   // MFMA C/D

struct __align__(16) U4 { u32 x, y, z, w; };
struct __align__(8)  U2 { u32 x, y; };

__device__ __forceinline__ float bf2f(u16 u){
  union { u32 i; float f; } v; v.i = ((u32)u) << 16; return v.f;
}
__device__ __forceinline__ u16 f2bf(float f){
  union { float f; u32 i; } v; v.f = f;
  u32 r = v.i + 0x7fffu + ((v.i >> 16) & 1u);
  return (u16)(r >> 16);
}
__device__ __forceinline__ u32 cvtpk_bf16(float lo, float hi){
  u32 r; asm("v_cvt_pk_bf16_f32 %0, %1, %2" : "=v"(r) : "v"(lo), "v"(hi)); return r;
}
__device__ __forceinline__ float exp2_hw(float x){
  float r; asm("v_exp_f32 %0, %1" : "=v"(r) : "v"(x)); return r;
}
__device__ __forceinline__ float gelu_t(float x){
  float y = 0.7978845608028654f * (x + 0.044715f * x * x * x);
  float e = __expf(2.f * y);
  return 0.5f * x * (2.f - 2.f / (e + 1.f));
}

// async global->LDS, 16B per lane; LDS dest is wave-uniform base + lane*16
__device__ __forceinline__ void gl2lds16(const u16* g, u16* l){
  __builtin_amdgcn_global_load_lds(
      (const __attribute__((address_space(1))) void*)g,
      (__attribute__((address_space(3))) void*)l, 16, 0, 0);
}

// ---------------- tiny zero block (OOB redirect target) --------------------
__global__ void zero_k(u16* p){ p[threadIdx.x] = 0; }

// ---------------- fp32 -> bf16 mirrors -------------------------------------
struct CvtJob  { const float* s; u16* d; int n; };
struct CvtJobs { CvtJob j[11]; };
__global__ __launch_bounds__(256) void cvt_all(CvtJobs jobs)
{
  const CvtJob jb = jobs.j[blockIdx.y];
  for (long i = (long)blockIdx.x*256 + threadIdx.x; i < jb.n; i += (long)gridDim.x*256)
    jb.d[i] = f2bf(jb.s[i]);
}

// ---------------- tiled weight transposes (fp32 src -> bf16 dst) -----------
struct TJob  { const float* s; u16* d; int R, C, srcLd, dstLd; };
struct TJobs { TJob j[10]; };
__global__ __launch_bounds__(256) void transpose_tiled(TJobs jobs)
{
  const TJob jb = jobs.j[blockIdx.y];
  const int tilesC = jb.C >> 6;
  const int nt = (jb.R >> 6) * tilesC;
  if ((int)blockIdx.x >= nt) return;
  const int tr = (blockIdx.x / tilesC) << 6, tc = (blockIdx.x % tilesC) << 6;
  __shared__ u16 t[64][65];
  const int tid = threadIdx.x;
  const int rr = tid >> 3, c8 = (tid & 7) * 8;
  #pragma unroll
  for (int p = 0; p < 2; ++p){
    const int r = rr + p*32;
    const float* s = &jb.s[(long)(tr + r)*jb.srcLd + tc + c8];
    #pragma unroll
    for (int j = 0; j < 8; ++j) t[r][c8 + j] = f2bf(s[j]);
  }
  __syncthreads();
  #pragma unroll
  for (int p = 0; p < 2; ++p){
    const int c = rr + p*32;
    u16 tmp[8];
    #pragma unroll
    for (int j = 0; j < 8; ++j) tmp[j] = t[c8 + j][c];
    *(U4*)&jb.d[(long)(tc + c)*jb.dstLd + tr + c8] = *(U4*)tmp;
  }
}

// ---------------- geglu weight interleave transpose (R11-proven) -----------
__global__ __launch_bounds__(256) void transpose_geglu(
    const float* __restrict__ src, u16* __restrict__ dst)
{
  __shared__ u16 t[64][65];
  const int ir0 = blockIdx.x << 6, k0 = blockIdx.y << 6;
  const int hc0 = ir0 >> 1;
  const int tid = threadIdx.x;
  const int rr = tid >> 3, c8 = (tid & 7) * 8;
  #pragma unroll
  for (int p = 0; p < 2; ++p){
    const int k = rr + p*32;
    const int scol = (c8 < 32) ? (hc0 + c8) : (FFI + hc0 + (c8 - 32));
    const float* s = &src[(long)(k0 + k)*(2*FFI) + scol];
    #pragma unroll
    for (int j = 0; j < 8; ++j){
      const int lc = c8 + j;
      const int grp = (lc < 32) ? 0 : 1;
      const int lg  = lc - grp*32;
      const int irl = (lg >> 4)*32 + grp*16 + (lg & 15);
      t[k][irl] = f2bf(s[j]);
    }
  }
  __syncthreads();
  #pragma unroll
  for (int p = 0; p < 2; ++p){
    const int c = rr + p*32;
    u16 tmp[8];
    #pragma unroll
    for (int j = 0; j < 8; ++j) tmp[j] = t[c8 + j][c];
    *(U4*)&dst[(long)(ir0 + c)*DIM + k0 + c8] = *(U4*)tmp;
  }
}

// ---------------- tiled bf16 transpose (v1T): R,C multiples of 64 ----------
__global__ __launch_bounds__(256) void transpose_tile(
    const u16* __restrict__ src, u16* __restrict__ dst,
    int srcLd, int dstLd)
{
  __shared__ u16 t[64][65];
  const int tr = blockIdx.y << 6, tc = blockIdx.x << 6;
  const int tid = threadIdx.x;
  const int rr = tid >> 3, c8 = (tid & 7) * 8;
  #pragma unroll
  for (int p = 0; p < 2; ++p){
    const int r = rr + p*32;
    U4 v = *(const U4*)&src[(long)(tr + r)*srcLd + tc + c8];
    const u16* pv = (const u16*)&v;
    #pragma unroll
    for (int j = 0; j < 8; ++j) t[r][c8 + j] = pv[j];
  }
  __syncthreads();
  #pragma unroll
  for (int p = 0; p < 2; ++p){
    const int c = rr + p*32;
    u16 tmp[8];
    #pragma unroll
    for (int j = 0; j < 8; ++j) tmp[j] = t[c8 + j][c];
    *(U4*)&dst[(long)(tc + c)*dstLd + tr + c8] = *(U4*)tmp;
  }
}

// v2 transpose with per-batch padding 77->80; pad columns ZEROED
__global__ __launch_bounds__(256) void transpose_v2(
    const u16* __restrict__ src, u16* __restrict__ dst)
{
  int idx = blockIdx.x*256 + threadIdx.x;
  if (idx >= DIM*640) return;
  int d = idx / 640, c = idx - d*640;
  int g = c / 80, j = c - g*80;
  u16 v = 0;
  if (j < 77) v = src[(long)(g*77 + j)*(2*DIM) + DIM + d];
  dst[(long)d*640 + c] = v;
}

// ---------------- LayerNorm: wave-per-row, vectorized, no LDS --------------
__global__ __launch_bounds__(256) void ln_k(
    const void* __restrict__ src, const u16* __restrict__ w,
    const u16* __restrict__ b, u16* __restrict__ dst, int srcf32)
{
  const int wave = threadIdx.x >> 6, lane = threadIdx.x & 63;
  const long row = (long)blockIdx.x*4 + wave;
  float x[10];
  if (srcf32){
    const float* s = (const float*)src + row*DIM;
    #pragma unroll
    for (int j = 0; j < 5; ++j){
      float2 v = *(const float2*)&s[lane*2 + j*128];
      x[j*2] = v.x; x[j*2+1] = v.y;
    }
  } else {
    const u16* s = (const u16*)src + row*DIM;
    #pragma unroll
    for (int j = 0; j < 5; ++j){
      u32 v = *(const u32*)&s[lane*2 + j*128];
      x[j*2]   = bf2f((u16)(v & 0xffffu));
      x[j*2+1] = bf2f((u16)(v >> 16));
    }
  }
  float sum = 0.f;
  #pragma unroll
  for (int i = 0; i < 10; ++i) sum += x[i];
  #pragma unroll
  for (int d = 1; d < 64; d <<= 1) sum += __shfl_xor(sum, d, 64);
  const float mean = sum * (1.f/DIM);
  float vq = 0.f;
  #pragma unroll
  for (int i = 0; i < 10; ++i){ float dd = x[i] - mean; vq += dd*dd; }
  #pragma unroll
  for (int d = 1; d < 64; d <<= 1) vq += __shfl_xor(vq, d, 64);
  const float rs = rsqrtf(vq * (1.f/DIM) + 1e-5f);
  u16* q = dst + row*DIM;
  #pragma unroll
  for (int j = 0; j < 5; ++j){
    const int off = lane*2 + j*128;
    u32 wv = *(const u32*)&w[off];
    u32 bv = *(const u32*)&b[off];
    float o0 = (x[j*2]   - mean)*rs*bf2f((u16)(wv & 0xffffu)) + bf2f((u16)(bv & 0xffffu));
    float o1 = (x[j*2+1] - mean)*rs*bf2f((u16)(wv >> 16))     + bf2f((u16)(bv >> 16));
    *(u32*)&q[off] = (u32)f2bf(o0) | ((u32)f2bf(o1) << 16);
  }
}

// ---------------- MFMA GEMM, 3-deep ring, counted vmcnt (R10-proven) -------
template<int BN>
__global__ __launch_bounds__(256) void gemm_bt(
    const u16* __restrict__ A, const u16* __restrict__ BT, void* __restrict__ C,
    int M, int N, int K, int lda, int ldb, int ldc,
    const u16* __restrict__ bias, const void* __restrict__ res, int ldr,
    int resf32, int outf32)
{
  constexpr int NT  = BN/32;
  constexpr int BCH = BN/16;
  constexpr int BPW = BCH/4;
  constexpr int LPW = 2 + BPW;
  __shared__ __align__(16) u16 sA[3][8*512];
  __shared__ __align__(16) u16 sB[3][BCH*512];
  const int tid  = threadIdx.x;
  const int wave = tid >> 6, lane = tid & 63;
  const int quad = lane >> 4, l16 = lane & 15;
  const int m0 = blockIdx.y * 128, n0 = blockIdx.x * BN;
  const int wm = (wave >> 1) * 64, wn = (wave & 1) * (BN/2);
  const int srow = lane & 15;
  const int scol = (lane >> 4) * 8;

  long aoff[2];
  #pragma unroll
  for (int i = 0; i < 2; ++i){
    int r = m0 + (wave*2 + i)*16 + srow;
    r = r < M ? r : M - 1;
    aoff[i] = (long)r*lda + scol;
  }
  long boff[BPW];
  #pragma unroll
  for (int i = 0; i < BPW; ++i){
    int r = n0 + (wave*BPW + i)*16 + srow;
    boff[i] = (long)r*ldb + scol;
  }

  auto stage = [&](int ks, int buf){
    const int kk = ks*32;
    #pragma unroll
    for (int i = 0; i < 2; ++i)   gl2lds16(&A[aoff[i] + kk],  &sA[buf][(wave*2 + i)*512]);
    #pragma unroll
    for (int i = 0; i < BPW; ++i) gl2lds16(&BT[boff[i] + kk], &sB[buf][(wave*BPW + i)*512]);
  };

  const int NS = K >> 5;
  f32x4 acc[4][NT] = {};
  stage(0, 0);
  if (NS > 1) stage(1, 1);

  int cur = 0;
  for (int ks = 0; ks < NS; ++ks){
    if (ks < NS - 1) asm volatile("s_waitcnt vmcnt(%0)" :: "n"(LPW) : "memory");
    else             asm volatile("s_waitcnt vmcnt(0)" ::: "memory");
    __builtin_amdgcn_sched_barrier(0);
    __builtin_amdgcn_s_barrier();
    __builtin_amdgcn_sched_barrier(0);
    if (ks + 2 < NS){
      int nbuf = cur + 2; if (nbuf >= 3) nbuf -= 3;
      stage(ks + 2, nbuf);
    }
    bf8 a[4], b[NT];
    #pragma unroll
    for (int mt = 0; mt < 4; ++mt)  a[mt] = *(const bf8*)&sA[cur][((wm>>4) + mt)*512 + lane*8];
    #pragma unroll
    for (int nt = 0; nt < NT; ++nt) b[nt] = *(const bf8*)&sB[cur][((wn>>4) + nt)*512 + lane*8];
    #pragma unroll
    for (int mt = 0; mt < 4; ++mt)
      #pragma unroll
      for (int nt = 0; nt < NT; ++nt)
        acc[mt][nt] = __builtin_amdgcn_mfma_f32_16x16x32_bf16(a[mt], b[nt], acc[mt][nt], 0, 0, 0);
    cur = (cur == 2) ? 0 : cur + 1;
  }
  #pragma unroll
  for (int mt = 0; mt < 4; ++mt){
    const int rl = wm + mt*16 + quad*4;
    #pragma unroll
    for (int nt = 0; nt < NT; ++nt){
      const int col = n0 + wn + nt*16 + l16;
      float bv = bias ? bf2f(bias[col]) : 0.f;
      #pragma unroll
      for (int r = 0; r < 4; ++r){
        int row = m0 + rl + r;
        if (row < M){
          float v = acc[mt][nt][r] + bv;
          if (res) v += resf32 ? ((const float*)res)[(long)row*ldr + col]
                               : bf2f(((const u16*)res)[(long)row*ldr + col]);
          if (outf32) ((float*)C)[(long)row*ldc + col] = v;
          else        ((u16*)C) [(long)row*ldc + col] = f2bf(v);
        }
      }
    }
  }
}

// ---------------- fused GEGLU GEMM: persistent-m, 3-ring, interleaved W ----
// grid (40,16): block owns one 128-col W tile and walks 4 m-tiles; the
// 3-deep counted-vmcnt ring flows ACROSS m-tile boundaries (one prologue
// per block, loads in flight through each epilogue). Epilogue mapping is
// the R11-verified h/gate interleave combine.
__global__ __launch_bounds__(256) void gemm_geglu(
    const u16* __restrict__ A, const u16* __restrict__ W, u16* __restrict__ C,
    const u16* __restrict__ bias)
{
  constexpr int LPW = 4;                 // 2 A + 2 W per wave per stage
  constexpr int NKS = DIM/32;            // 20 K-steps per m-tile
  constexpr int MT  = 4;                 // m-tiles per block
  __shared__ __align__(16) u16 sA[3][8*512];
  __shared__ __align__(16) u16 sB[3][8*512];
  const int tid  = threadIdx.x;
  const int wave = tid >> 6, lane = tid & 63;
  const int quad = lane >> 4, l16 = lane & 15;
  const int n0 = blockIdx.x * 128;
  const int mbase = blockIdx.y * (MT*128);
  const int wm = (wave >> 1) * 64, wn = (wave & 1) * 64;
  const int srow = lane & 15;
  const int scol = (lane >> 4) * 8;

  long aoff[2], boff[2];
  #pragma unroll
  for (int i = 0; i < 2; ++i){
    aoff[i] = (long)(mbase + (wave*2 + i)*16 + srow)*DIM + scol;
    boff[i] = (long)(n0 + (wave*2 + i)*16 + srow)*DIM + scol;
  }

  auto stage = [&](int t, int k, int buf){
    const long adel = (long)t*(128*DIM) + k*32;
    const long bdel = (long)k*32;
    #pragma unroll
    for (int i = 0; i < 2; ++i){
      gl2lds16(&A[aoff[i] + adel], &sA[buf][(wave*2 + i)*512]);
      gl2lds16(&W[boff[i] + bdel], &sB[buf][(wave*2 + i)*512]);
    }
  };

  f32x4 acc[4][4] = {};
  stage(0, 0, 0);
  stage(0, 1, 1);

  int cur = 0, nk = 2, ntile = 0;        // next stage index (t=ntile,k=nk)
  for (int t = 0; t < MT; ++t){
    for (int k = 0; k < NKS; ++k){
      const bool last = (t == MT-1) && (k == NKS-1);
      if (!last) asm volatile("s_waitcnt vmcnt(%0)" :: "n"(LPW) : "memory");
      else       asm volatile("s_waitcnt vmcnt(0)" ::: "memory");
      __builtin_amdgcn_sched_barrier(0);
      __builtin_amdgcn_s_barrier();
      __builtin_amdgcn_sched_barrier(0);
      if (ntile < MT){                   // stage step s+2 if it exists
        int nbuf = cur + 2; if (nbuf >= 3) nbuf -= 3;
        stage(ntile, nk, nbuf);
        if (++nk == NKS){ nk = 0; ++ntile; }
      }
      bf8 a[4], b[4];
      #pragma unroll
      for (int mt = 0; mt < 4; ++mt) a[mt] = *(const bf8*)&sA[cur][((wm>>4) + mt)*512 + lane*8];
      #pragma unroll
      for (int nt = 0; nt < 4; ++nt) b[nt] = *(const bf8*)&sB[cur][((wn>>4) + nt)*512 + lane*8];
      #pragma unroll
      for (int mt = 0; mt < 4; ++mt)
        #pragma unroll
        for (int nt = 0; nt < 4; ++nt)
          acc[mt][nt] = __builtin_amdgcn_mfma_f32_16x16x32_bf16(a[mt], b[nt], acc[mt][nt], 0, 0, 0);
      cur = (cur == 2) ? 0 : cur + 1;
    }
    // epilogue for m-tile t (ring loads for t+1 stay in flight)
    const int m0 = mbase + t*128;
    #pragma unroll
    for (int mt = 0; mt < 4; ++mt){
      const int rl = wm + mt*16 + quad*4;
      #pragma unroll
      for (int p = 0; p < 2; ++p){
        const int col = ((n0 + wn) >> 1) + p*16 + l16;
        const float bh = bf2f(bias[col]);
        const float bg = bf2f(bias[FFI + col]);
        #pragma unroll
        for (int r = 0; r < 4; ++r){
          int row = m0 + rl + r;
          float h = acc[mt][2*p][r]   + bh;
          float g = acc[mt][2*p+1][r] + bg;
          C[(long)row*FFI + col] = f2bf(h * gelu_t(g));
        }
      }
    }
    #pragma unroll
    for (int mt = 0; mt < 4; ++mt)
      #pragma unroll
      for (int nt = 0; nt < 4; ++nt)
        #pragma unroll
        for (int r = 0; r < 4; ++r) acc[mt][nt][r] = 0.f;
  }
}

// ---------------- MFMA flash attention (R8 protocol + setprio/exp-hw) ------
// g==0 shortcut: temporal KV = [frame0; frame0] (former==0); softmax over
// duplicated keys == softmax over one copy, so process 32 chunks not 64.
template<int MODE>
__global__ __launch_bounds__(256) void attn_k(
    const u16* __restrict__ qbuf, const u16* __restrict__ kbuf,
    const u16* __restrict__ vT, u16* __restrict__ out,
    const u16* __restrict__ zblk)
{
  constexpr int QLD  = MODE ? DIM      : 3*DIM;
  constexpr int KLD  = MODE ? 2*DIM    : 3*DIM;
  constexpr int KCOL = MODE ? 0        : DIM;
  constexpr int VLD  = MODE ? DIM      : TOK;
  constexpr int NK   = MODE ? 77       : 2*SEQ;
  constexpr int NCH  = MODE ? 3        : 64;   // 32-key chunks
  constexpr float C1   = SCALE * 1.4426950408889634f;   // scale * log2(e)
  constexpr float THRR = 8.0f / C1;                     // defer-max threshold

  const int qt = blockIdx.x, h = blockIdx.y, g = blockIdx.z;
  const int tid = threadIdx.x, wave = tid >> 6, lane = tid & 63;
  const int quad = lane >> 4, l16 = lane & 15;
  const int NCHeff = (MODE == 0 && g == 0) ? 32 : NCH;

  __shared__ __align__(16) u16 Kb[2][6*512];   // 2 key-groups x 3 d-slices
  __shared__ __align__(16) u16 Vb[2][5*512];   // 5 d-groups x 32 keys
  __shared__ __align__(16) u16 Ps[4][16*40];

  const int qrow0 = g*SEQ + qt*64;
  bf8 qf[3];
  {
    const long qbase = (long)(qrow0 + wave*16 + l16)*QLD + h*HD;
    #pragma unroll
    for (int ks = 0; ks < 3; ++ks){
      const int d = ks*32 + quad*8;
      const u16* src = (d < HD) ? &qbuf[qbase + d] : zblk;
      qf[ks] = *(const bf8*)src;
    }
  }

  const int former = (g == 0) ? 0 : (g - 1);

  const bool kc1v = (wave < 2);
  const int  vc0  = (wave + 2) & 3;
  const bool vc1v = (wave == 2);

  long ko[2] = {0,0}, koB[2] = {0,0}, vo[2] = {0,0}, voB[2] = {0,0};
  bool koob[2];
  #pragma unroll
  for (int j = 0; j < 2; ++j){
    const int ci = wave + 4*j;
    const int ck = ci/3, ks = ci - ck*3;
    const int d = ks*32 + quad*8;
    koob[j] = (d >= HD);
    if (MODE == 0){
      const int dcl = koob[j] ? 0 : d;
      const int row = ck*16 + l16;
      ko[j]  = (long)row*KLD + KCOL + h*HD + dcl;
      koB[j] = ko[j] + (long)former*SEQ*KLD;
    }
  }
  if (MODE == 0){
    vo[0]  = (long)(h*HD + vc0*16 + l16)*VLD + quad*8;
    vo[1]  = (long)(h*HD + 64    + l16)*VLD + quad*8;   // vi=4
    voB[0] = vo[0] + (long)former*SEQ;
    voB[1] = vo[1] + (long)former*SEQ;
  }

  auto stageM0 = [&](int buf){
    gl2lds16(koob[0] ? zblk : &kbuf[ko[0]], &Kb[buf][(wave)*512]);
    if (kc1v) gl2lds16(koob[1] ? zblk : &kbuf[ko[1]], &Kb[buf][(wave+4)*512]);
    gl2lds16(&vT[vo[0]], &Vb[buf][vc0*512]);
    if (vc1v) gl2lds16(&vT[vo[1]], &Vb[buf][4*512]);
    ko[0] += 32L*KLD; ko[1] += 32L*KLD;
    vo[0] += 32; vo[1] += 32;
  };
  auto stageM1 = [&](int c, int buf){
    #pragma unroll
    for (int ci = 0; ci < 6; ++ci){
      if ((ci & 3) == wave){
        const int ck = ci / 3, ks = ci % 3;
        const int d  = ks*32 + quad*8;
        const int rl = ck*16 + l16;
        int j = c*32 + rl; j = j < NK ? j : NK-1;
        const u16* src = (d < HD) ? &kbuf[((long)g*77 + j)*KLD + KCOL + h*HD + d] : zblk;
        gl2lds16(src, &Kb[buf][ci*512]);
      }
    }
    #pragma unroll
    for (int vi = 0; vi < 5; ++vi){
      if (((vi + 2) & 3) == wave){
        const int dd = vi*16 + l16;
        int key = c*32 + quad*8;
        const u16* src = (key < 80) ? &vT[(long)(h*HD + dd)*VLD + g*80 + key] : zblk;
        gl2lds16(src, &Vb[buf][vi*512]);
      }
    }
  };

  f32x4 o[5] = {};
  float mrun = -1e30f, lrun = 0.f, nmc = 0.f;

  if (MODE == 0) stageM0(0); else stageM1(0, 0);
  __syncthreads();
  int cur = 0;

  for (int c = 0; c < NCHeff; ++c){
    if (c + 1 < NCHeff){
      if (MODE == 0){
        if (c + 1 == 32){
          ko[0] = koB[0]; ko[1] = koB[1];
          vo[0] = voB[0]; vo[1] = voB[1];
        }
        stageM0(cur ^ 1);
      } else {
        stageM1(c + 1, cur ^ 1);
      }
    }

    f32x4 s0 = {}, s1 = {};
    __builtin_amdgcn_s_setprio(1);
    #pragma unroll
    for (int ks = 0; ks < 3; ++ks){
      bf8 kf0 = *(const bf8*)&Kb[cur][ks*512     + lane*8];
      bf8 kf1 = *(const bf8*)&Kb[cur][(3+ks)*512 + lane*8];
      s0 = __builtin_amdgcn_mfma_f32_16x16x32_bf16(kf0, qf[ks], s0, 0, 0, 0);
      s1 = __builtin_amdgcn_mfma_f32_16x16x32_bf16(kf1, qf[ks], s1, 0, 0, 0);
    }
    __builtin_amdgcn_s_setprio(0);

    if (MODE == 1){
      const int kg = c*32 + quad*4;
      #pragma unroll
      for (int r = 0; r < 4; ++r){
        if (kg + r >= NK)      s0[r] = -1e30f;
        if (kg + 16 + r >= NK) s1[r] = -1e30f;
      }
    }
    float mxs = fmaxf(fmaxf(fmaxf(s0[0],s0[1]), fmaxf(s0[2],s0[3])),
                      fmaxf(fmaxf(s1[0],s1[1]), fmaxf(s1[2],s1[3])));
    if (!__all(mxs - mrun <= THRR)){
      float mx = fmaxf(mxs, __shfl_xor(mxs, 16, 64));
      mx = fmaxf(mx, __shfl_xor(mx, 32, 64));
      float mn = fmaxf(mrun, mx);
      float al = exp2_hw((mrun - mn)*C1);
      mrun = mn; nmc = -mrun*C1;
      lrun *= al;
      float a0 = __shfl(al, quad*4 + 0, 16);
      float a1 = __shfl(al, quad*4 + 1, 16);
      float a2 = __shfl(al, quad*4 + 2, 16);
      float a3 = __shfl(al, quad*4 + 3, 16);
      #pragma unroll
      for (int dt = 0; dt < 5; ++dt){
        o[dt][0] *= a0; o[dt][1] *= a1; o[dt][2] *= a2; o[dt][3] *= a3;
      }
    }
    #pragma unroll
    for (int r = 0; r < 4; ++r){
      s0[r] = exp2_hw(__builtin_fmaf(s0[r], C1, nmc));
      s1[r] = exp2_hw(__builtin_fmaf(s1[r], C1, nmc));
    }
    lrun += ((s0[0]+s0[1])+(s0[2]+s0[3])) + ((s1[0]+s1[1])+(s1[2]+s1[3]));

    U2 w01, w23;
    w01.x = cvtpk_bf16(s0[0], s0[1]);  w01.y = cvtpk_bf16(s0[2], s0[3]);
    w23.x = cvtpk_bf16(s1[0], s1[1]);  w23.y = cvtpk_bf16(s1[2], s1[3]);
    U2* pr = (U2*)&Ps[wave][l16*40];
    pr[quad]     = w01;
    pr[4 + quad] = w23;
    asm volatile("s_waitcnt lgkmcnt(0)" ::: "memory");
    __builtin_amdgcn_sched_barrier(0);
    bf8 pf = *(const bf8*)&Ps[wave][l16*40 + quad*8];
    __builtin_amdgcn_s_setprio(1);
    #pragma unroll
    for (int dt = 0; dt < 5; ++dt){
      bf8 vf = *(const bf8*)&Vb[cur][dt*512 + lane*8];
      o[dt] = __builtin_amdgcn_mfma_f32_16x16x32_bf16(pf, vf, o[dt], 0, 0, 0);
    }
    __builtin_amdgcn_s_setprio(0);
    __syncthreads();
    cur ^= 1;
  }

  lrun += __shfl_xor(lrun, 16, 64);
  lrun += __shfl_xor(lrun, 32, 64);

  float linv[4];
  #pragma unroll
  for (int r = 0; r < 4; ++r)
    linv[r] = __builtin_amdgcn_rcpf(__shfl(lrun, quad*4 + r, 16));
  const int orow0 = qrow0 + wave*16 + quad*4;
  #pragma unroll
  for (int dt = 0; dt < 5; ++dt){
    const int col = h*HD + dt*16 + l16;
    #pragma unroll
    for (int r = 0; r < 4; ++r)
      out[(long)(orow0 + r)*DIM + col] = f2bf(o[dt][r] * linv[r]);
  }
}

// ---------------- host orchestration ---------------------------------------
extern "C" void kernel_launch(void* const* d_in, const int* in_sizes, int n_in,
                              void* d_out, int out_size, void* d_ws, size_t ws_size,
                              hipStream_t stream)
{
  const float* hidden = (const float*)d_in[0];
  const float* enc    = (const float*)d_in[1];
  const float* ln1w = (const float*)d_in[3],  *ln1b = (const float*)d_in[4];
  const float* q1   = (const float*)d_in[5],  *k1   = (const float*)d_in[6];
  const float* v1   = (const float*)d_in[7],  *o1w  = (const float*)d_in[8];
  const float* o1b  = (const float*)d_in[9];
  const float* ln2w = (const float*)d_in[10], *ln2b = (const float*)d_in[11];
  const float* q2   = (const float*)d_in[12], *k2   = (const float*)d_in[13];
  const float* v2   = (const float*)d_in[14], *o2w  = (const float*)d_in[15];
  const float* o2b  = (const float*)d_in[16];
  const float* ln3w = (const float*)d_in[17], *ln3b = (const float*)d_in[18];
  const float* fw1  = (const float*)d_in[19], *fb1  = (const float*)d_in[20];
  const float* fw2  = (const float*)d_in[21], *fb2  = (const float*)d_in[22];

  u16* ws = (u16*)d_ws;
  u16* Wqkv1T = ws;                           // 1920*640
  u16* o1T    = Wqkv1T + 1920*640;            // 640*640
  u16* q2T    = o1T    + 640*640;
  u16* Wkv2T  = q2T    + 640*640;             // 1280*768
  u16* o2T    = Wkv2T  + 1280*768;
  u16* W1T    = o2T    + 640*640;             // 5120*640 (interleaved W1iT)
  u16* W2T    = W1T    + 5120*640;            // 640*2560
  u16* xbuf   = W2T    + 640*2560;            // 8192*640
  u16* qkv1   = xbuf   + (size_t)TOK*DIM;     // 8192*1920
  u16* v1T    = qkv1   + (size_t)TOK*3*DIM;   // 640*8192
  u16* ffin   = qkv1;                         // alias: 8192*2560 == qkv1+v1T
  u16* attnb  = v1T    + (size_t)DIM*TOK;     // 8192*640
  u16* hid2   = attnb  + (size_t)TOK*DIM;
  u16* hid3   = hid2   + (size_t)TOK*DIM;
  u16* q2buf  = hid3   + (size_t)TOK*DIM;
  u16* kv2    = q2buf  + (size_t)TOK*DIM;     // 616*1280
  u16* v2T    = kv2    + (size_t)ETOK*2*DIM;  // 640*640 + pad
  u16* encm   = v2T    + 640*640 + 64;        // 616*768
  u16* bln1w  = encm   + (size_t)ETOK*CROSS;
  u16* bln1b  = bln1w + DIM;
  u16* bo1b   = bln1b + DIM;
  u16* bln2w  = bo1b  + DIM;
  u16* bln2b  = bln2w + DIM;
  u16* bo2b   = bln2b + DIM;
  u16* bln3w  = bo2b  + DIM;
  u16* bln3b  = bln3w + DIM;
  u16* bfb2   = bln3b + DIM;
  u16* bfb1   = bfb2  + DIM;                  // 5120
  u16* zblk   = bfb1  + 2*FFI;                // 64 u16 of zeros (16B aligned)
  u16* wsend  = zblk  + 64;
  const size_t needed = ((size_t)(wsend - ws) + 64) * 2;
  if (ws_size < needed) return;

  dim3 blk(256);
  zero_k<<<1, 64, 0, stream>>>(zblk);

  // ---- stage 0: bf16 mirrors of fp32 inputs ----
  CvtJobs jobs;
  jobs.j[0]  = { enc,  encm,  ETOK*CROSS };
  jobs.j[1]  = { ln1w, bln1w, DIM };
  jobs.j[2]  = { ln1b, bln1b, DIM };
  jobs.j[3]  = { o1b,  bo1b,  DIM };
  jobs.j[4]  = { ln2w, bln2w, DIM };
  jobs.j[5]  = { ln2b, bln2b, DIM };
  jobs.j[6]  = { o2b,  bo2b,  DIM };
  jobs.j[7]  = { ln3w, bln3w, DIM };
  jobs.j[8]  = { ln3b, bln3b, DIM };
  jobs.j[9]  = { fb2,  bfb2,  DIM };
  jobs.j[10] = { fb1,  bfb1,  2*FFI };
  cvt_all<<<dim3(64,11), blk, 0, stream>>>(jobs);

  // ---- fused weight transposes into B^T layouts (9 jobs; fw1 separate) ----
  TJobs tj;
  tj.j[0] = { q1,  Wqkv1T,            640, 640,  640,  640 };
  tj.j[1] = { k1,  Wqkv1T + 640*640,  640, 640,  640,  640 };
  tj.j[2] = { v1,  Wqkv1T + 1280*640, 640, 640,  640,  640 };
  tj.j[3] = { o1w, o1T,               640, 640,  640,  640 };
  tj.j[4] = { q2,  q2T,               640, 640,  640,  640 };
  tj.j[5] = { k2,  Wkv2T,             768, 640,  640,  768 };
  tj.j[6] = { v2,  Wkv2T + 640*768,   768, 640,  640,  768 };
  tj.j[7] = { o2w, o2T,               640, 640,  640,  640 };
  tj.j[8] = { fw2, W2T,               2560,640,  640,  2560 };
  tj.j[9] = { nullptr, nullptr, 0, 0, 0, 0 };
  transpose_tiled<<<dim3(400,9), blk, 0, stream>>>(tj);
  transpose_geglu<<<dim3(80,10), blk, 0, stream>>>(fw1, W1T);

  // ---- block 1: LN1(fp32) -> qkv -> temporal attention -> o1 + res(fp32) ----
  ln_k<<<TOK/4, blk, 0, stream>>>(hidden, bln1w, bln1b, xbuf, 1);
  gemm_bt<128><<<dim3(15,64), blk, 0, stream>>>(xbuf, Wqkv1T, qkv1,
      TOK, 3*DIM, DIM, DIM, DIM, 3*DIM, nullptr, nullptr, 0, 0, 0);
  transpose_tile<<<dim3(10,128), blk, 0, stream>>>(qkv1 + 2*DIM, v1T, 3*DIM, TOK);
  attn_k<0><<<dim3(16,8,8), blk, 0, stream>>>(qkv1, qkv1, v1T, attnb, zblk);
  gemm_bt<64><<<dim3(10,64), blk, 0, stream>>>(attnb, o1T, hid2,
      TOK, DIM, DIM, DIM, DIM, DIM, bo1b, hidden, DIM, 1, 0);

  // ---- block 2: LN2 -> q2 / kv2 -> cross attention -> o2 + residual ----
  ln_k<<<TOK/4, blk, 0, stream>>>(hid2, bln2w, bln2b, xbuf, 0);
  gemm_bt<64><<<dim3(10,64), blk, 0, stream>>>(xbuf, q2T, q2buf,
      TOK, DIM, DIM, DIM, DIM, DIM, nullptr, nullptr, 0, 0, 0);
  gemm_bt<64><<<dim3(20,5), blk, 0, stream>>>(encm, Wkv2T, kv2,
      ETOK, 2*DIM, CROSS, CROSS, CROSS, 2*DIM, nullptr, nullptr, 0, 0, 0);
  transpose_v2<<<dim3((DIM*640 + 255)/256), blk, 0, stream>>>(kv2, v2T);
  attn_k<1><<<dim3(16,8,8), blk, 0, stream>>>(q2buf, kv2, v2T, attnb, zblk);
  gemm_bt<64><<<dim3(10,64), blk, 0, stream>>>(attnb, o2T, hid3,
      TOK, DIM, DIM, DIM, DIM, DIM, bo2b, hid2, DIM, 0, 0);

  // ---- block 3: LN3 -> GEGLU FF -> out(fp32) + residual ----
  ln_k<<<TOK/4, blk, 0, stream>>>(hid3, bln3w, bln3b, xbuf, 0);
  gemm_geglu<<<dim3(40,16), blk, 0, stream>>>(xbuf, W1T, ffin, bfb1);
  gemm_bt<64><<<dim3(10,64), blk, 0, stream>>>(ffin, W2T, d_out,
      TOK, DIM, FFI, FFI, FFI, DIM, bfb2, hid3, DIM, 0, 1);
}

// Round 13
// 646.820 us; speedup vs baseline: 1.0872x; 1.0872x over previous
//
#include <hip/hip_runtime.h>
#include <stdint.h>

#define TOK   8192        // 8 frames * 1024 tokens
#define DIM   640
#define HEADS 8
#define HD    80
#define SEQ   1024
#define CROSS 768
#define ETOK  616         // 8 * 77 encoder tokens
#define FFI   2560        // FF inner (half of 5120 proj)
#define SCALE 0.11180339887498949f

typedef unsigned short u16;
typedef unsigned int   u32;

using bf8   = __attribute__((ext_vector_type(8))) short;   // 8 bf16 (4 VGPRs)
using f32x4 = __attribute__((ext_vector_type(4))) float;   // MFMA C/D

struct __align__(16) U4 { u32 x, y, z, w; };
struct __align__(8)  U2 { u32 x, y; };

__device__ __forceinline__ float bf2f(u16 u){
  union { u32 i; float f; } v; v.i = ((u32)u) << 16; return v.f;
}
__device__ __forceinline__ u16 f2bf(float f){
  union { float f; u32 i; } v; v.f = f;
  u32 r = v.i + 0x7fffu + ((v.i >> 16) & 1u);
  return (u16)(r >> 16);
}
__device__ __forceinline__ u32 cvtpk_bf16(float lo, float hi){
  u32 r; asm("v_cvt_pk_bf16_f32 %0, %1, %2" : "=v"(r) : "v"(lo), "v"(hi)); return r;
}
__device__ __forceinline__ float exp2_hw(float x){
  float r; asm("v_exp_f32 %0, %1" : "=v"(r) : "v"(x)); return r;
}
__device__ __forceinline__ float gelu_t(float x){
  float y = 0.7978845608028654f * (x + 0.044715f * x * x * x);
  float e = __expf(2.f * y);
  return 0.5f * x * (2.f - 2.f / (e + 1.f));
}

// async global->LDS, 16B per lane; LDS dest is wave-uniform base + lane*16
__device__ __forceinline__ void gl2lds16(const u16* g, u16* l){
  __builtin_amdgcn_global_load_lds(
      (const __attribute__((address_space(1))) void*)g,
      (__attribute__((address_space(3))) void*)l, 16, 0, 0);
}

// ---------------- tiny zero block (OOB redirect target) --------------------
__global__ void zero_k(u16* p){ p[threadIdx.x] = 0; }

// ---------------- fp32 -> bf16 mirrors -------------------------------------
struct CvtJob  { const float* s; u16* d; int n; };
struct CvtJobs { CvtJob j[11]; };
__global__ __launch_bounds__(256) void cvt_all(CvtJobs jobs)
{
  const CvtJob jb = jobs.j[blockIdx.y];
  for (long i = (long)blockIdx.x*256 + threadIdx.x; i < jb.n; i += (long)gridDim.x*256)
    jb.d[i] = f2bf(jb.s[i]);
}

// ---------------- tiled weight transposes (fp32 src -> bf16 dst) -----------
struct TJob  { const float* s; u16* d; int R, C, srcLd, dstLd; };
struct TJobs { TJob j[10]; };
__global__ __launch_bounds__(256) void transpose_tiled(TJobs jobs)
{
  const TJob jb = jobs.j[blockIdx.y];
  const int tilesC = jb.C >> 6;
  const int nt = (jb.R >> 6) * tilesC;
  if ((int)blockIdx.x >= nt) return;
  const int tr = (blockIdx.x / tilesC) << 6, tc = (blockIdx.x % tilesC) << 6;
  __shared__ u16 t[64][65];
  const int tid = threadIdx.x;
  const int rr = tid >> 3, c8 = (tid & 7) * 8;
  #pragma unroll
  for (int p = 0; p < 2; ++p){
    const int r = rr + p*32;
    const float* s = &jb.s[(long)(tr + r)*jb.srcLd + tc + c8];
    #pragma unroll
    for (int j = 0; j < 8; ++j) t[r][c8 + j] = f2bf(s[j]);
  }
  __syncthreads();
  #pragma unroll
  for (int p = 0; p < 2; ++p){
    const int c = rr + p*32;
    u16 tmp[8];
    #pragma unroll
    for (int j = 0; j < 8; ++j) tmp[j] = t[c8 + j][c];
    *(U4*)&jb.d[(long)(tc + c)*jb.dstLd + tr + c8] = *(U4*)tmp;
  }
}

// ---------------- geglu weight interleave transpose (R11-proven) -----------
__global__ __launch_bounds__(256) void transpose_geglu(
    const float* __restrict__ src, u16* __restrict__ dst)
{
  __shared__ u16 t[64][65];
  const int ir0 = blockIdx.x << 6, k0 = blockIdx.y << 6;
  const int hc0 = ir0 >> 1;
  const int tid = threadIdx.x;
  const int rr = tid >> 3, c8 = (tid & 7) * 8;
  #pragma unroll
  for (int p = 0; p < 2; ++p){
    const int k = rr + p*32;
    const int scol = (c8 < 32) ? (hc0 + c8) : (FFI + hc0 + (c8 - 32));
    const float* s = &src[(long)(k0 + k)*(2*FFI) + scol];
    #pragma unroll
    for (int j = 0; j < 8; ++j){
      const int lc = c8 + j;
      const int grp = (lc < 32) ? 0 : 1;
      const int lg  = lc - grp*32;
      const int irl = (lg >> 4)*32 + grp*16 + (lg & 15);
      t[k][irl] = f2bf(s[j]);
    }
  }
  __syncthreads();
  #pragma unroll
  for (int p = 0; p < 2; ++p){
    const int c = rr + p*32;
    u16 tmp[8];
    #pragma unroll
    for (int j = 0; j < 8; ++j) tmp[j] = t[c8 + j][c];
    *(U4*)&dst[(long)(ir0 + c)*DIM + k0 + c8] = *(U4*)tmp;
  }
}

// ---------------- tiled bf16 transpose (v1T): R,C multiples of 64 ----------
__global__ __launch_bounds__(256) void transpose_tile(
    const u16* __restrict__ src, u16* __restrict__ dst,
    int srcLd, int dstLd)
{
  __shared__ u16 t[64][65];
  const int tr = blockIdx.y << 6, tc = blockIdx.x << 6;
  const int tid = threadIdx.x;
  const int rr = tid >> 3, c8 = (tid & 7) * 8;
  #pragma unroll
  for (int p = 0; p < 2; ++p){
    const int r = rr + p*32;
    U4 v = *(const U4*)&src[(long)(tr + r)*srcLd + tc + c8];
    const u16* pv = (const u16*)&v;
    #pragma unroll
    for (int j = 0; j < 8; ++j) t[r][c8 + j] = pv[j];
  }
  __syncthreads();
  #pragma unroll
  for (int p = 0; p < 2; ++p){
    const int c = rr + p*32;
    u16 tmp[8];
    #pragma unroll
    for (int j = 0; j < 8; ++j) tmp[j] = t[c8 + j][c];
    *(U4*)&dst[(long)(tc + c)*dstLd + tr + c8] = *(U4*)tmp;
  }
}

// v2 transpose with per-batch padding 77->80; pad columns ZEROED
__global__ __launch_bounds__(256) void transpose_v2(
    const u16* __restrict__ src, u16* __restrict__ dst)
{
  int idx = blockIdx.x*256 + threadIdx.x;
  if (idx >= DIM*640) return;
  int d = idx / 640, c = idx - d*640;
  int g = c / 80, j = c - g*80;
  u16 v = 0;
  if (j < 77) v = src[(long)(g*77 + j)*(2*DIM) + DIM + d];
  dst[(long)d*640 + c] = v;
}

// ---------------- LayerNorm: wave-per-row, vectorized, no LDS --------------
__global__ __launch_bounds__(256) void ln_k(
    const void* __restrict__ src, const u16* __restrict__ w,
    const u16* __restrict__ b, u16* __restrict__ dst, int srcf32)
{
  const int wave = threadIdx.x >> 6, lane = threadIdx.x & 63;
  const long row = (long)blockIdx.x*4 + wave;
  float x[10];
  if (srcf32){
    const float* s = (const float*)src + row*DIM;
    #pragma unroll
    for (int j = 0; j < 5; ++j){
      float2 v = *(const float2*)&s[lane*2 + j*128];
      x[j*2] = v.x; x[j*2+1] = v.y;
    }
  } else {
    const u16* s = (const u16*)src + row*DIM;
    #pragma unroll
    for (int j = 0; j < 5; ++j){
      u32 v = *(const u32*)&s[lane*2 + j*128];
      x[j*2]   = bf2f((u16)(v & 0xffffu));
      x[j*2+1] = bf2f((u16)(v >> 16));
    }
  }
  float sum = 0.f;
  #pragma unroll
  for (int i = 0; i < 10; ++i) sum += x[i];
  #pragma unroll
  for (int d = 1; d < 64; d <<= 1) sum += __shfl_xor(sum, d, 64);
  const float mean = sum * (1.f/DIM);
  float vq = 0.f;
  #pragma unroll
  for (int i = 0; i < 10; ++i){ float dd = x[i] - mean; vq += dd*dd; }
  #pragma unroll
  for (int d = 1; d < 64; d <<= 1) vq += __shfl_xor(vq, d, 64);
  const float rs = rsqrtf(vq * (1.f/DIM) + 1e-5f);
  u16* q = dst + row*DIM;
  #pragma unroll
  for (int j = 0; j < 5; ++j){
    const int off = lane*2 + j*128;
    u32 wv = *(const u32*)&w[off];
    u32 bv = *(const u32*)&b[off];
    float o0 = (x[j*2]   - mean)*rs*bf2f((u16)(wv & 0xffffu)) + bf2f((u16)(bv & 0xffffu));
    float o1 = (x[j*2+1] - mean)*rs*bf2f((u16)(wv >> 16))     + bf2f((u16)(bv >> 16));
    *(u32*)&q[off] = (u32)f2bf(o0) | ((u32)f2bf(o1) << 16);
  }
}

// ---------------- MFMA GEMM, 3-deep ring, counted vmcnt (R10-proven) -------
template<int BN>
__global__ __launch_bounds__(256) void gemm_bt(
    const u16* __restrict__ A, const u16* __restrict__ BT, void* __restrict__ C,
    int M, int N, int K, int lda, int ldb, int ldc,
    const u16* __restrict__ bias, const void* __restrict__ res, int ldr,
    int resf32, int outf32)
{
  constexpr int NT  = BN/32;
  constexpr int BCH = BN/16;
  constexpr int BPW = BCH/4;
  constexpr int LPW = 2 + BPW;
  __shared__ __align__(16) u16 sA[3][8*512];
  __shared__ __align__(16) u16 sB[3][BCH*512];
  const int tid  = threadIdx.x;
  const int wave = tid >> 6, lane = tid & 63;
  const int quad = lane >> 4, l16 = lane & 15;
  const int m0 = blockIdx.y * 128, n0 = blockIdx.x * BN;
  const int wm = (wave >> 1) * 64, wn = (wave & 1) * (BN/2);
  const int srow = lane & 15;
  const int scol = (lane >> 4) * 8;

  long aoff[2];
  #pragma unroll
  for (int i = 0; i < 2; ++i){
    int r = m0 + (wave*2 + i)*16 + srow;
    r = r < M ? r : M - 1;
    aoff[i] = (long)r*lda + scol;
  }
  long boff[BPW];
  #pragma unroll
  for (int i = 0; i < BPW; ++i){
    int r = n0 + (wave*BPW + i)*16 + srow;
    boff[i] = (long)r*ldb + scol;
  }

  auto stage = [&](int ks, int buf){
    const int kk = ks*32;
    #pragma unroll
    for (int i = 0; i < 2; ++i)   gl2lds16(&A[aoff[i] + kk],  &sA[buf][(wave*2 + i)*512]);
    #pragma unroll
    for (int i = 0; i < BPW; ++i) gl2lds16(&BT[boff[i] + kk], &sB[buf][(wave*BPW + i)*512]);
  };

  const int NS = K >> 5;
  f32x4 acc[4][NT] = {};
  stage(0, 0);
  if (NS > 1) stage(1, 1);

  int cur = 0;
  for (int ks = 0; ks < NS; ++ks){
    if (ks < NS - 1) asm volatile("s_waitcnt vmcnt(%0)" :: "n"(LPW) : "memory");
    else             asm volatile("s_waitcnt vmcnt(0)" ::: "memory");
    __builtin_amdgcn_sched_barrier(0);
    __builtin_amdgcn_s_barrier();
    __builtin_amdgcn_sched_barrier(0);
    if (ks + 2 < NS){
      int nbuf = cur + 2; if (nbuf >= 3) nbuf -= 3;
      stage(ks + 2, nbuf);
    }
    bf8 a[4], b[NT];
    #pragma unroll
    for (int mt = 0; mt < 4; ++mt)  a[mt] = *(const bf8*)&sA[cur][((wm>>4) + mt)*512 + lane*8];
    #pragma unroll
    for (int nt = 0; nt < NT; ++nt) b[nt] = *(const bf8*)&sB[cur][((wn>>4) + nt)*512 + lane*8];
    #pragma unroll
    for (int mt = 0; mt < 4; ++mt)
      #pragma unroll
      for (int nt = 0; nt < NT; ++nt)
        acc[mt][nt] = __builtin_amdgcn_mfma_f32_16x16x32_bf16(a[mt], b[nt], acc[mt][nt], 0, 0, 0);
    cur = (cur == 2) ? 0 : cur + 1;
  }
  #pragma unroll
  for (int mt = 0; mt < 4; ++mt){
    const int rl = wm + mt*16 + quad*4;
    #pragma unroll
    for (int nt = 0; nt < NT; ++nt){
      const int col = n0 + wn + nt*16 + l16;
      float bv = bias ? bf2f(bias[col]) : 0.f;
      #pragma unroll
      for (int r = 0; r < 4; ++r){
        int row = m0 + rl + r;
        if (row < M){
          float v = acc[mt][nt][r] + bv;
          if (res) v += resf32 ? ((const float*)res)[(long)row*ldr + col]
                               : bf2f(((const u16*)res)[(long)row*ldr + col]);
          if (outf32) ((float*)C)[(long)row*ldc + col] = v;
          else        ((u16*)C) [(long)row*ldc + col] = f2bf(v);
        }
      }
    }
  }
}

// ---------------- fused GEGLU GEMM, 128x128 interleaved, single acc --------
// R11-measured version (124 us): W = W1iT (h/gate pair-interleaved, 32-row
// blocks). acc[mt][2p]=h, acc[mt][2p+1]=g for out col ((n0+wn)>>1)+p*16+l16.
// 2-buffer dbuf, grid (40,64).
__global__ __launch_bounds__(256) void gemm_geglu(
    const u16* __restrict__ A, const u16* __restrict__ W, u16* __restrict__ C,
    const u16* __restrict__ bias)
{
  __shared__ __align__(16) u16 sA[2][8*512];
  __shared__ __align__(16) u16 sB[2][8*512];
  const int tid  = threadIdx.x;
  const int wave = tid >> 6, lane = tid & 63;
  const int quad = lane >> 4, l16 = lane & 15;
  const int m0 = blockIdx.y * 128, n0 = blockIdx.x * 128;
  const int wm = (wave >> 1) * 64, wn = (wave & 1) * 64;
  const int srow = lane & 15;
  const int scol = (lane >> 4) * 8;

  long aoff[2], boff[2];
  #pragma unroll
  for (int i = 0; i < 2; ++i){
    aoff[i] = (long)(m0 + (wave*2 + i)*16 + srow)*DIM + scol;
    boff[i] = (long)(n0 + (wave*2 + i)*16 + srow)*DIM + scol;
  }

  f32x4 acc[4][4] = {};
  #pragma unroll
  for (int i = 0; i < 2; ++i){
    gl2lds16(&A[aoff[i]], &sA[0][(wave*2 + i)*512]);
    gl2lds16(&W[boff[i]], &sB[0][(wave*2 + i)*512]);
  }
  __syncthreads();

  int cur = 0;
  for (int k0 = 0; ; ){
    const int kn = k0 + 32;
    if (kn < DIM){
      #pragma unroll
      for (int i = 0; i < 2; ++i){
        gl2lds16(&A[aoff[i] + kn], &sA[cur^1][(wave*2 + i)*512]);
        gl2lds16(&W[boff[i] + kn], &sB[cur^1][(wave*2 + i)*512]);
      }
    }
    bf8 a[4], b[4];
    #pragma unroll
    for (int mt = 0; mt < 4; ++mt) a[mt] = *(const bf8*)&sA[cur][((wm>>4) + mt)*512 + lane*8];
    #pragma unroll
    for (int nt = 0; nt < 4; ++nt) b[nt] = *(const bf8*)&sB[cur][((wn>>4) + nt)*512 + lane*8];
    #pragma unroll
    for (int mt = 0; mt < 4; ++mt)
      #pragma unroll
      for (int nt = 0; nt < 4; ++nt)
        acc[mt][nt] = __builtin_amdgcn_mfma_f32_16x16x32_bf16(a[mt], b[nt], acc[mt][nt], 0, 0, 0);
    k0 = kn;
    if (k0 >= DIM) break;
    __syncthreads();
    cur ^= 1;
  }
  // epilogue: combine h (nt=2p) with gate (nt=2p+1) in-thread
  #pragma unroll
  for (int mt = 0; mt < 4; ++mt){
    const int rl = wm + mt*16 + quad*4;
    #pragma unroll
    for (int p = 0; p < 2; ++p){
      const int col = ((n0 + wn) >> 1) + p*16 + l16;
      const float bh = bf2f(bias[col]);
      const float bg = bf2f(bias[FFI + col]);
      #pragma unroll
      for (int r = 0; r < 4; ++r){
        int row = m0 + rl + r;
        float h = acc[mt][2*p][r]   + bh;
        float g = acc[mt][2*p+1][r] + bg;
        C[(long)row*FFI + col] = f2bf(h * gelu_t(g));
      }
    }
  }
}

// ---------------- MFMA flash attention (R12-proven: setprio/exp-hw/g0) -----
template<int MODE>
__global__ __launch_bounds__(256) void attn_k(
    const u16* __restrict__ qbuf, const u16* __restrict__ kbuf,
    const u16* __restrict__ vT, u16* __restrict__ out,
    const u16* __restrict__ zblk)
{
  constexpr int QLD  = MODE ? DIM      : 3*DIM;
  constexpr int KLD  = MODE ? 2*DIM    : 3*DIM;
  constexpr int KCOL = MODE ? 0        : DIM;
  constexpr int VLD  = MODE ? DIM      : TOK;
  constexpr int NK   = MODE ? 77       : 2*SEQ;
  constexpr int NCH  = MODE ? 3        : 64;   // 32-key chunks
  constexpr float C1   = SCALE * 1.4426950408889634f;   // scale * log2(e)
  constexpr float THRR = 8.0f / C1;                     // defer-max threshold

  const int qt = blockIdx.x, h = blockIdx.y, g = blockIdx.z;
  const int tid = threadIdx.x, wave = tid >> 6, lane = tid & 63;
  const int quad = lane >> 4, l16 = lane & 15;
  const int NCHeff = (MODE == 0 && g == 0) ? 32 : NCH;

  __shared__ __align__(16) u16 Kb[2][6*512];   // 2 key-groups x 3 d-slices
  __shared__ __align__(16) u16 Vb[2][5*512];   // 5 d-groups x 32 keys
  __shared__ __align__(16) u16 Ps[4][16*40];

  const int qrow0 = g*SEQ + qt*64;
  bf8 qf[3];
  {
    const long qbase = (long)(qrow0 + wave*16 + l16)*QLD + h*HD;
    #pragma unroll
    for (int ks = 0; ks < 3; ++ks){
      const int d = ks*32 + quad*8;
      const u16* src = (d < HD) ? &qbuf[qbase + d] : zblk;
      qf[ks] = *(const bf8*)src;
    }
  }

  const int former = (g == 0) ? 0 : (g - 1);

  const bool kc1v = (wave < 2);
  const int  vc0  = (wave + 2) & 3;
  const bool vc1v = (wave == 2);

  long ko[2] = {0,0}, koB[2] = {0,0}, vo[2] = {0,0}, voB[2] = {0,0};
  bool koob[2];
  #pragma unroll
  for (int j = 0; j < 2; ++j){
    const int ci = wave + 4*j;
    const int ck = ci/3, ks = ci - ck*3;
    const int d = ks*32 + quad*8;
    koob[j] = (d >= HD);
    if (MODE == 0){
      const int dcl = koob[j] ? 0 : d;
      const int row = ck*16 + l16;
      ko[j]  = (long)row*KLD + KCOL + h*HD + dcl;
      koB[j] = ko[j] + (long)former*SEQ*KLD;
    }
  }
  if (MODE == 0){
    vo[0]  = (long)(h*HD + vc0*16 + l16)*VLD + quad*8;
    vo[1]  = (long)(h*HD + 64    + l16)*VLD + quad*8;   // vi=4
    voB[0] = vo[0] + (long)former*SEQ;
    voB[1] = vo[1] + (long)former*SEQ;
  }

  auto stageM0 = [&](int buf){
    gl2lds16(koob[0] ? zblk : &kbuf[ko[0]], &Kb[buf][(wave)*512]);
    if (kc1v) gl2lds16(koob[1] ? zblk : &kbuf[ko[1]], &Kb[buf][(wave+4)*512]);
    gl2lds16(&vT[vo[0]], &Vb[buf][vc0*512]);
    if (vc1v) gl2lds16(&vT[vo[1]], &Vb[buf][4*512]);
    ko[0] += 32L*KLD; ko[1] += 32L*KLD;
    vo[0] += 32; vo[1] += 32;
  };
  auto stageM1 = [&](int c, int buf){
    #pragma unroll
    for (int ci = 0; ci < 6; ++ci){
      if ((ci & 3) == wave){
        const int ck = ci / 3, ks = ci % 3;
        const int d  = ks*32 + quad*8;
        const int rl = ck*16 + l16;
        int j = c*32 + rl; j = j < NK ? j : NK-1;
        const u16* src = (d < HD) ? &kbuf[((long)g*77 + j)*KLD + KCOL + h*HD + d] : zblk;
        gl2lds16(src, &Kb[buf][ci*512]);
      }
    }
    #pragma unroll
    for (int vi = 0; vi < 5; ++vi){
      if (((vi + 2) & 3) == wave){
        const int dd = vi*16 + l16;
        int key = c*32 + quad*8;
        const u16* src = (key < 80) ? &vT[(long)(h*HD + dd)*VLD + g*80 + key] : zblk;
        gl2lds16(src, &Vb[buf][vi*512]);
      }
    }
  };

  f32x4 o[5] = {};
  float mrun = -1e30f, lrun = 0.f, nmc = 0.f;

  if (MODE == 0) stageM0(0); else stageM1(0, 0);
  __syncthreads();
  int cur = 0;

  for (int c = 0; c < NCHeff; ++c){
    if (c + 1 < NCHeff){
      if (MODE == 0){
        if (c + 1 == 32){
          ko[0] = koB[0]; ko[1] = koB[1];
          vo[0] = voB[0]; vo[1] = voB[1];
        }
        stageM0(cur ^ 1);
      } else {
        stageM1(c + 1, cur ^ 1);
      }
    }

    f32x4 s0 = {}, s1 = {};
    __builtin_amdgcn_s_setprio(1);
    #pragma unroll
    for (int ks = 0; ks < 3; ++ks){
      bf8 kf0 = *(const bf8*)&Kb[cur][ks*512     + lane*8];
      bf8 kf1 = *(const bf8*)&Kb[cur][(3+ks)*512 + lane*8];
      s0 = __builtin_amdgcn_mfma_f32_16x16x32_bf16(kf0, qf[ks], s0, 0, 0, 0);
      s1 = __builtin_amdgcn_mfma_f32_16x16x32_bf16(kf1, qf[ks], s1, 0, 0, 0);
    }
    __builtin_amdgcn_s_setprio(0);

    if (MODE == 1){
      const int kg = c*32 + quad*4;
      #pragma unroll
      for (int r = 0; r < 4; ++r){
        if (kg + r >= NK)      s0[r] = -1e30f;
        if (kg + 16 + r >= NK) s1[r] = -1e30f;
      }
    }
    float mxs = fmaxf(fmaxf(fmaxf(s0[0],s0[1]), fmaxf(s0[2],s0[3])),
                      fmaxf(fmaxf(s1[0],s1[1]), fmaxf(s1[2],s1[3])));
    if (!__all(mxs - mrun <= THRR)){
      float mx = fmaxf(mxs, __shfl_xor(mxs, 16, 64));
      mx = fmaxf(mx, __shfl_xor(mx, 32, 64));
      float mn = fmaxf(mrun, mx);
      float al = exp2_hw((mrun - mn)*C1);
      mrun = mn; nmc = -mrun*C1;
      lrun *= al;
      float a0 = __shfl(al, quad*4 + 0, 16);
      float a1 = __shfl(al, quad*4 + 1, 16);
      float a2 = __shfl(al, quad*4 + 2, 16);
      float a3 = __shfl(al, quad*4 + 3, 16);
      #pragma unroll
      for (int dt = 0; dt < 5; ++dt){
        o[dt][0] *= a0; o[dt][1] *= a1; o[dt][2] *= a2; o[dt][3] *= a3;
      }
    }
    #pragma unroll
    for (int r = 0; r < 4; ++r){
      s0[r] = exp2_hw(__builtin_fmaf(s0[r], C1, nmc));
      s1[r] = exp2_hw(__builtin_fmaf(s1[r], C1, nmc));
    }
    lrun += ((s0[0]+s0[1])+(s0[2]+s0[3])) + ((s1[0]+s1[1])+(s1[2]+s1[3]));

    U2 w01, w23;
    w01.x = cvtpk_bf16(s0[0], s0[1]);  w01.y = cvtpk_bf16(s0[2], s0[3]);
    w23.x = cvtpk_bf16(s1[0], s1[1]);  w23.y = cvtpk_bf16(s1[2], s1[3]);
    U2* pr = (U2*)&Ps[wave][l16*40];
    pr[quad]     = w01;
    pr[4 + quad] = w23;
    asm volatile("s_waitcnt lgkmcnt(0)" ::: "memory");
    __builtin_amdgcn_sched_barrier(0);
    bf8 pf = *(const bf8*)&Ps[wave][l16*40 + quad*8];
    __builtin_amdgcn_s_setprio(1);
    #pragma unroll
    for (int dt = 0; dt < 5; ++dt){
      bf8 vf = *(const bf8*)&Vb[cur][dt*512 + lane*8];
      o[dt] = __builtin_amdgcn_mfma_f32_16x16x32_bf16(pf, vf, o[dt], 0, 0, 0);
    }
    __builtin_amdgcn_s_setprio(0);
    __syncthreads();
    cur ^= 1;
  }

  lrun += __shfl_xor(lrun, 16, 64);
  lrun += __shfl_xor(lrun, 32, 64);

  float linv[4];
  #pragma unroll
  for (int r = 0; r < 4; ++r)
    linv[r] = __builtin_amdgcn_rcpf(__shfl(lrun, quad*4 + r, 16));
  const int orow0 = qrow0 + wave*16 + quad*4;
  #pragma unroll
  for (int dt = 0; dt < 5; ++dt){
    const int col = h*HD + dt*16 + l16;
    #pragma unroll
    for (int r = 0; r < 4; ++r)
      out[(long)(orow0 + r)*DIM + col] = f2bf(o[dt][r] * linv[r]);
  }
}

// ---------------- host orchestration ---------------------------------------
extern "C" void kernel_launch(void* const* d_in, const int* in_sizes, int n_in,
                              void* d_out, int out_size, void* d_ws, size_t ws_size,
                              hipStream_t stream)
{
  const float* hidden = (const float*)d_in[0];
  const float* enc    = (const float*)d_in[1];
  const float* ln1w = (const float*)d_in[3],  *ln1b = (const float*)d_in[4];
  const float* q1   = (const float*)d_in[5],  *k1   = (const float*)d_in[6];
  const float* v1   = (const float*)d_in[7],  *o1w  = (const float*)d_in[8];
  const float* o1b  = (const float*)d_in[9];
  const float* ln2w = (const float*)d_in[10], *ln2b = (const float*)d_in[11];
  const float* q2   = (const float*)d_in[12], *k2   = (const float*)d_in[13];
  const float* v2   = (const float*)d_in[14], *o2w  = (const float*)d_in[15];
  const float* o2b  = (const float*)d_in[16];
  const float* ln3w = (const float*)d_in[17], *ln3b = (const float*)d_in[18];
  const float* fw1  = (const float*)d_in[19], *fb1  = (const float*)d_in[20];
  const float* fw2  = (const float*)d_in[21], *fb2  = (const float*)d_in[22];

  u16* ws = (u16*)d_ws;
  u16* Wqkv1T = ws;                           // 1920*640
  u16* o1T    = Wqkv1T + 1920*640;            // 640*640
  u16* q2T    = o1T    + 640*640;
  u16* Wkv2T  = q2T    + 640*640;             // 1280*768
  u16* o2T    = Wkv2T  + 1280*768;
  u16* W1T    = o2T    + 640*640;             // 5120*640 (interleaved W1iT)
  u16* W2T    = W1T    + 5120*640;            // 640*2560
  u16* xbuf   = W2T    + 640*2560;            // 8192*640
  u16* qkv1   = xbuf   + (size_t)TOK*DIM;     // 8192*1920
  u16* v1T    = qkv1   + (size_t)TOK*3*DIM;   // 640*8192
  u16* ffin   = qkv1;                         // alias: 8192*2560 == qkv1+v1T
  u16* attnb  = v1T    + (size_t)DIM*TOK;     // 8192*640
  u16* hid2   = attnb  + (size_t)TOK*DIM;
  u16* hid3   = hid2   + (size_t)TOK*DIM;
  u16* q2buf  = hid3   + (size_t)TOK*DIM;
  u16* kv2    = q2buf  + (size_t)TOK*DIM;     // 616*1280
  u16* v2T    = kv2    + (size_t)ETOK*2*DIM;  // 640*640 + pad
  u16* encm   = v2T    + 640*640 + 64;        // 616*768
  u16* bln1w  = encm   + (size_t)ETOK*CROSS;
  u16* bln1b  = bln1w + DIM;
  u16* bo1b   = bln1b + DIM;
  u16* bln2w  = bo1b  + DIM;
  u16* bln2b  = bln2w + DIM;
  u16* bo2b   = bln2b + DIM;
  u16* bln3w  = bo2b  + DIM;
  u16* bln3b  = bln3w + DIM;
  u16* bfb2   = bln3b + DIM;
  u16* bfb1   = bfb2  + DIM;                  // 5120
  u16* zblk   = bfb1  + 2*FFI;                // 64 u16 of zeros (16B aligned)
  u16* wsend  = zblk  + 64;
  const size_t needed = ((size_t)(wsend - ws) + 64) * 2;
  if (ws_size < needed) return;

  dim3 blk(256);
  zero_k<<<1, 64, 0, stream>>>(zblk);

  // ---- stage 0: bf16 mirrors of fp32 inputs ----
  CvtJobs jobs;
  jobs.j[0]  = { enc,  encm,  ETOK*CROSS };
  jobs.j[1]  = { ln1w, bln1w, DIM };
  jobs.j[2]  = { ln1b, bln1b, DIM };
  jobs.j[3]  = { o1b,  bo1b,  DIM };
  jobs.j[4]  = { ln2w, bln2w, DIM };
  jobs.j[5]  = { ln2b, bln2b, DIM };
  jobs.j[6]  = { o2b,  bo2b,  DIM };
  jobs.j[7]  = { ln3w, bln3w, DIM };
  jobs.j[8]  = { ln3b, bln3b, DIM };
  jobs.j[9]  = { fb2,  bfb2,  DIM };
  jobs.j[10] = { fb1,  bfb1,  2*FFI };
  cvt_all<<<dim3(64,11), blk, 0, stream>>>(jobs);

  // ---- fused weight transposes into B^T layouts (9 jobs; fw1 separate) ----
  TJobs tj;
  tj.j[0] = { q1,  Wqkv1T,            640, 640,  640,  640 };
  tj.j[1] = { k1,  Wqkv1T + 640*640,  640, 640,  640,  640 };
  tj.j[2] = { v1,  Wqkv1T + 1280*640, 640, 640,  640,  640 };
  tj.j[3] = { o1w, o1T,               640, 640,  640,  640 };
  tj.j[4] = { q2,  q2T,               640, 640,  640,  640 };
  tj.j[5] = { k2,  Wkv2T,             768, 640,  640,  768 };
  tj.j[6] = { v2,  Wkv2T + 640*768,   768, 640,  640,  768 };
  tj.j[7] = { o2w, o2T,               640, 640,  640,  640 };
  tj.j[8] = { fw2, W2T,               2560,640,  640,  2560 };
  tj.j[9] = { nullptr, nullptr, 0, 0, 0, 0 };
  transpose_tiled<<<dim3(400,9), blk, 0, stream>>>(tj);
  transpose_geglu<<<dim3(80,10), blk, 0, stream>>>(fw1, W1T);

  // ---- block 1: LN1(fp32) -> qkv -> temporal attention -> o1 + res(fp32) ----
  ln_k<<<TOK/4, blk, 0, stream>>>(hidden, bln1w, bln1b, xbuf, 1);
  gemm_bt<128><<<dim3(15,64), blk, 0, stream>>>(xbuf, Wqkv1T, qkv1,
      TOK, 3*DIM, DIM, DIM, DIM, 3*DIM, nullptr, nullptr, 0, 0, 0);
  transpose_tile<<<dim3(10,128), blk, 0, stream>>>(qkv1 + 2*DIM, v1T, 3*DIM, TOK);
  attn_k<0><<<dim3(16,8,8), blk, 0, stream>>>(qkv1, qkv1, v1T, attnb, zblk);
  gemm_bt<64><<<dim3(10,64), blk, 0, stream>>>(attnb, o1T, hid2,
      TOK, DIM, DIM, DIM, DIM, DIM, bo1b, hidden, DIM, 1, 0);

  // ---- block 2: LN2 -> q2 / kv2 -> cross attention -> o2 + residual ----
  ln_k<<<TOK/4, blk, 0, stream>>>(hid2, bln2w, bln2b, xbuf, 0);
  gemm_bt<64><<<dim3(10,64), blk, 0, stream>>>(xbuf, q2T, q2buf,
      TOK, DIM, DIM, DIM, DIM, DIM, nullptr, nullptr, 0, 0, 0);
  gemm_bt<64><<<dim3(20,5), blk, 0, stream>>>(encm, Wkv2T, kv2,
      ETOK, 2*DIM, CROSS, CROSS, CROSS, 2*DIM, nullptr, nullptr, 0, 0, 0);
  transpose_v2<<<dim3((DIM*640 + 255)/256), blk, 0, stream>>>(kv2, v2T);
  attn_k<1><<<dim3(16,8,8), blk, 0, stream>>>(q2buf, kv2, v2T, attnb, zblk);
  gemm_bt<64><<<dim3(10,64), blk, 0, stream>>>(attnb, o2T, hid3,
      TOK, DIM, DIM, DIM, DIM, DIM, bo2b, hid2, DIM, 0, 0);

  // ---- block 3: LN3 -> GEGLU FF -> out(fp32) + residual ----
  ln_k<<<TOK/4, blk, 0, stream>>>(hid3, bln3w, bln3b, xbuf, 0);
  gemm_geglu<<<dim3(40,64), blk, 0, stream>>>(xbuf, W1T, ffin, bfb1);
  gemm_bt<64><<<dim3(10,64), blk, 0, stream>>>(ffin, W2T, d_out,
      TOK, DIM, FFI, FFI, FFI, DIM, bfb2, hid3, DIM, 0, 1);
}